// Round 9
// baseline (327.459 us; speedup 1.0000x reference)
//
#include <hip/hip_runtime.h>
#include <hip/hip_bf16.h>

typedef unsigned short u16;
typedef __attribute__((ext_vector_type(8))) short short8;
typedef __attribute__((ext_vector_type(4))) float floatx4;

#define TOKENS 8192
#define KDIM   2048
#define NFEAT  8192
#define R_     4
#define N1_    2048
#define M1_    1024

#define BM 256
#define BN 256
#define BK 64
#define NKT (KDIM / BK)   // 32 K-tiles

__device__ __forceinline__ u16 f2bf(float f) {
  union { float f; unsigned u; } v; v.f = f;
  unsigned r = v.u + 0x7fffu + ((v.u >> 16) & 1u);  // RNE
  return (u16)(r >> 16);
}

// ---- P1: fused prep: blocks [0,16384) cvt x->bf16; blocks [16384,24576) build Wf ----
#define CVT_BLOCKS 16384
struct u16x4 { u16 a, b, c, d; };
__global__ void k_prep(const float4* __restrict__ x4, u16x4* __restrict__ xb,
                       const float* __restrict__ A, const float* __restrict__ Bm,
                       const int* __restrict__ p_inv, const int* __restrict__ q,
                       u16* __restrict__ Wf) {
  __shared__ int pfs[KDIM];
  int bid = blockIdx.x;
  if (bid < CVT_BLOCKS) {
    int i = bid * 256 + threadIdx.x;
    float4 v = x4[i];
    u16x4 o; o.a = f2bf(v.x); o.b = f2bf(v.y); o.c = f2bf(v.z); o.d = f2bf(v.w);
    xb[i] = o;
  } else {
    int f = bid - CVT_BLOCKS;
    for (int i = threadIdx.x; i < KDIM; i += 256) pfs[p_inv[i]] = i;
    __syncthreads();
    int k0 = threadIdx.x * 8;
    int qf = q[f];
    int n = qf >> 2, jq = qf & 3;
    const float* An = A + (size_t)n * M1_;
    float bc[8];
#pragma unroll
    for (int r = 0; r < R_; ++r) {
      bc[r * 2 + 0] = Bm[r * 8 + 0 * 4 + jq];
      bc[r * 2 + 1] = Bm[r * 8 + 1 * 4 + jq];
    }
    u16 w[8];
#pragma unroll
    for (int i = 0; i < 8; ++i) {
      int c = pfs[k0 + i];
      int m1 = c >> 1, m2 = c & 1;
      float acc = 0.f;
#pragma unroll
      for (int r = 0; r < R_; ++r)
        acc += An[(size_t)r * (N1_ * M1_) + m1] * bc[r * 2 + m2];
      w[i] = f2bf(acc);
    }
    *(short8*)(Wf + (size_t)f * KDIM + k0) = *(const short8*)w;
  }
}

// ---- GEMM: 256x256, BK=64, 8 waves (2Mx4N), 2-phase/iter compiler-scheduled
//      inner (fine lgkmcnt by compiler), VMCNT(0)+BAR publish at phase end.
//      XCD-round 4x8 rectangular tile mapping (R7).
#define GLD16(gp, lp) __builtin_amdgcn_global_load_lds( \
    (const __attribute__((address_space(1))) void*)(gp), \
    (__attribute__((address_space(3))) void*)(lp), 16, 0, 0)

#define FENCE asm volatile("" ::: "memory")
#define BAR   do { FENCE; __builtin_amdgcn_s_barrier(); FENCE; } while (0)
#define VMCNT(n) asm volatile("s_waitcnt vmcnt(" #n ")" ::: "memory")

__global__ __launch_bounds__(512, 2) void k_gemm(
    const u16* __restrict__ X, const u16* __restrict__ W,
    const float* __restrict__ bias, float* __restrict__ out) {
  // slot (64KB x2): A-half0 16K | A-half1 16K | B-half0 16K | B-half1 16K
  __shared__ __align__(16) char lds[2 * 65536];

  // L2-rectangle mapping: per (xcd, round): 4 tM x 8 tN working set (~12 MB)
  int bid = blockIdx.x;
  int xcd = bid & 7;
  int loc = bid >> 3;
  int u = loc >> 5, v = loc & 31;
  int tM = xcd * 4 + (v >> 3);
  int tN = u * 8 + (v & 7);
  int rowBase = tM * BM, colBase = tN * BN;

  int tid = threadIdx.x, lane = tid & 63, wave = tid >> 6;
  int wm = wave >> 2;                // 0..1 : rows [wm*128, +128)
  int wn = wave & 3;                 // 0..3 : cols [wn*64, +64)

  // staging: pre-swizzled global source, linear LDS dest (both-sides involution)
  int srow = tid >> 3;
  int scol = ((tid & 7) ^ (srow & 7)) * 8;
  const u16* Asrc = X + (size_t)(rowBase + srow) * KDIM + scol;
  const u16* Bsrc = W + (size_t)(colBase + srow) * KDIM + scol;

  auto SA = [&](int slot, int half, int kt) {
#pragma unroll
    for (int jj = 0; jj < 2; ++jj)
      GLD16(Asrc + (size_t)(half * 128 + jj * 64) * KDIM + kt * 64,
            &lds[slot * 65536 + half * 16384 + jj * 8192 + tid * 16]);
  };
  auto SB = [&](int slot, int half, int kt) {
#pragma unroll
    for (int jj = 0; jj < 2; ++jj)
      GLD16(Bsrc + (size_t)(half * 128 + jj * 64) * KDIM + kt * 64,
            &lds[slot * 65536 + 32768 + half * 16384 + jj * 8192 + tid * 16]);
  };

  // fragment reads: row*128 + ((kk*4 + lane>>4) ^ (lane&7))*16
  int l15 = lane & 15, lhi = lane >> 4, l7 = lane & 7;
  int x0 = (lhi ^ l7) * 16;
  int x1 = ((4 + lhi) ^ l7) * 16;
  int abase = wm * 16384 + l15 * 128;
  int bbase = 32768 + (wn >> 1) * 16384 + ((wn & 1) * 64 + l15) * 128;

  auto RA = [&](int slot, int m, int kk) -> short8 {
    return *(const short8*)&lds[slot * 65536 + abase + m * 2048 + (kk ? x1 : x0)];
  };
  auto RB = [&](int slot, int n, int kk) -> short8 {
    return *(const short8*)&lds[slot * 65536 + bbase + n * 2048 + (kk ? x1 : x0)];
  };

  floatx4 acc[8][4] = {};

  // one K-tile phase: stage next tile, then compiler-scheduled reads+MFMAs
  auto PHASE = [&](int cs, int t, bool full) {
    if (full) {
      SA(cs ^ 1, 0, t + 1); SA(cs ^ 1, 1, t + 1);
      SB(cs ^ 1, 0, t + 1); SB(cs ^ 1, 1, t + 1);
    }
    short8 af[8], bf[4];
    // kk = 0
#pragma unroll
    for (int m = 0; m < 8; ++m) af[m] = RA(cs, m, 0);
#pragma unroll
    for (int n = 0; n < 4; ++n) bf[n] = RB(cs, n, 0);
    __builtin_amdgcn_s_setprio(1);
#pragma unroll
    for (int m = 0; m < 8; ++m)
#pragma unroll
      for (int n = 0; n < 4; ++n)
        acc[m][n] = __builtin_amdgcn_mfma_f32_16x16x32_bf16(af[m], bf[n], acc[m][n], 0, 0, 0);
    __builtin_amdgcn_s_setprio(0);
    // kk = 1
#pragma unroll
    for (int m = 0; m < 8; ++m) af[m] = RA(cs, m, 1);
#pragma unroll
    for (int n = 0; n < 4; ++n) bf[n] = RB(cs, n, 1);
    __builtin_amdgcn_s_setprio(1);
#pragma unroll
    for (int m = 0; m < 8; ++m)
#pragma unroll
      for (int n = 0; n < 4; ++n)
        acc[m][n] = __builtin_amdgcn_mfma_f32_16x16x32_bf16(af[m], bf[n], acc[m][n], 0, 0, 0);
    __builtin_amdgcn_s_setprio(0);
    if (full) { VMCNT(0); BAR; }
  };

  // ---- prologue: slot0 = tile0
  SA(0, 0, 0); SA(0, 1, 0); SB(0, 0, 0); SB(0, 1, 0);
  VMCNT(0); BAR;

#pragma unroll 1
  for (int it = 0; it < NKT / 2; ++it) {
    PHASE(0, 2 * it, true);
    PHASE(1, 2 * it + 1, 2 * it + 1 < NKT - 1);
  }

  // ---- epilogue: C = acc + bias; C/D layout col=lane&15, row=(lane>>4)*4+reg
  float bv[4];
#pragma unroll
  for (int n = 0; n < 4; ++n)
    bv[n] = bias[colBase + wn * 64 + n * 16 + l15];
#pragma unroll
  for (int m = 0; m < 8; ++m) {
    int r0 = wm * 128 + m * 16 + (lhi << 2);
#pragma unroll
    for (int n = 0; n < 4; ++n) {
      size_t basep = (size_t)(rowBase + r0) * NFEAT + colBase + wn * 64 + n * 16 + l15;
#pragma unroll
      for (int reg = 0; reg < 4; ++reg)
        out[basep + (size_t)reg * NFEAT] = acc[m][n][reg] + bv[n];
    }
  }
}

extern "C" void kernel_launch(void* const* d_in, const int* in_sizes, int n_in,
                              void* d_out, int out_size, void* d_ws, size_t ws_size,
                              hipStream_t stream) {
  const float* x     = (const float*)d_in[0];
  const float* A     = (const float*)d_in[1];
  const float* Bm    = (const float*)d_in[2];
  const float* bias  = (const float*)d_in[3];
  const int*   p_inv = (const int*)d_in[4];
  const int*   q     = (const int*)d_in[5];
  float* out = (float*)d_out;

  u16* Xb = (u16*)d_ws;
  u16* Wf = (u16*)((char*)d_ws + (size_t)TOKENS * KDIM * 2);

  k_prep<<<CVT_BLOCKS + NFEAT, 256, 0, stream>>>((const float4*)x, (u16x4*)Xb, A, Bm, p_inv, q, Wf);
  k_gemm<<<(TOKENS / BM) * (NFEAT / BN), 512, 0, stream>>>(Xb, Wf, bias, out);
}